// Round 12
// baseline (767.669 us; speedup 1.0000x reference)
//
#include <hip/hip_runtime.h>
#include <hip/hip_bf16.h>
#include <math.h>

typedef __hip_bfloat16 bf16;
typedef __attribute__((ext_vector_type(8))) short bf16x8;   // 8 bf16 = 4 VGPR
typedef __attribute__((ext_vector_type(4))) float f32x4;    // MFMA acc

#define BATCH   16
#define SEQLEN  2048
#define INDIM   64
#define HIDD    256
#define STATE_D 256
#define MLPD    1024
#define OUTD    128
#define NLAYERS 4
#define M_TOK   (BATCH*SEQLEN)     // 32768 tokens
#define CHUNK   64
#define NCHUNK  (SEQLEN/CHUNK)     // 32 chunks per batch

// ---- ALL-BF16 activation chain; complex-interleaved states (R10) ---------
__device__ float g_carry[512*512];          // fp32 carries [chunk][2s|2s+1]
__device__ bf16  g_hb [(size_t)M_TOK*256];
__device__ bf16  g_yb [(size_t)M_TOK*256];
__device__ bf16  g_bub[(size_t)M_TOK*512];  // raw Bu, then scan states (in place)
// per-layer packed weights (hoisted out of the layer loop)
__device__ bf16  g_Bnb[NLAYERS*512*256];    // B_norm rows interleaved: 2s=re, 2s+1=im
__device__ bf16  g_Cwb[NLAYERS*256*512];    // cols interleaved: 2s=Cre, 2s+1=-Cim
__device__ bf16  g_Whb[NLAYERS*1024*256];
__device__ bf16  g_Wob[NLAYERS*256*1024];

#define SB_HB  0
#define SB_YB  1
#define SB_BUB 2
#define SB_BNB 4
#define SB_CWB 5
#define SB_WHB 6
#define SB_WOB 7

__device__ __forceinline__ bf16* bufb(int sel){
  switch(sel){
    case SB_HB:  return g_hb;  case SB_YB:  return g_yb;
    case SB_BUB: return g_bub;
    case SB_BNB: return g_Bnb; case SB_CWB: return g_Cwb;
    case SB_WHB: return g_Whb; default:     return g_Wob; }
}

// async global->LDS, 16B per lane. LDS dest is wave-uniform base + lane*16.
__device__ __forceinline__ void gld_lds16(const void* g, void* l){
  __builtin_amdgcn_global_load_lds(
      (const __attribute__((address_space(1))) unsigned int*)g,
      (__attribute__((address_space(3))) unsigned int*)l, 16, 0, 0);
}

// Branch-free exact-GELU via Abramowitz-Stegun 7.1.26 erf (|err|<=1.5e-7).
__device__ __forceinline__ float fast_gelu(float v){
  const float x  = v * 0.70710678118654752f;
  const float ax = fabsf(x);
  const float t  = __builtin_amdgcn_rcpf(fmaf(0.3275911f, ax, 1.0f));
  float p = fmaf(t, 1.061405429f, -1.453152027f);
  p = fmaf(t, p, 1.421413741f);
  p = fmaf(t, p, -0.284496736f);
  p = fmaf(t, p, 0.254829592f);
  p = p * t;
  const float e = __expf(-ax * ax);
  const float erf_ax = fmaf(-p, e, 1.0f);
  const float erf_x  = copysignf(erf_ax, x);
  return 0.5f * v * (1.0f + erf_x);
}

// pairwise add of 2 packed bf16 lanes in fp32, repack to bf16
__device__ __forceinline__ unsigned int bf2_add(unsigned int a, unsigned int b){
  float alo = __uint_as_float(a << 16), ahi = __uint_as_float(a & 0xffff0000u);
  float blo = __uint_as_float(b << 16), bhi = __uint_as_float(b & 0xffff0000u);
  bf16 l = __float2bfloat16(alo + blo);
  bf16 h = __float2bfloat16(ahi + bhi);
  return (unsigned int)(*reinterpret_cast<unsigned short*>(&l))
       | ((unsigned int)(*reinterpret_cast<unsigned short*>(&h)) << 16);
}

// lam_s = exp(-exp(nu)) * (cos(exp(th)) + i sin(exp(th)))
__device__ __forceinline__ void lam_of(const float* __restrict__ nu_log,
                                       const float* __restrict__ th_log,
                                       int s, float& lr, float& li)
{
  float nu  = expf(nu_log[s]);
  float th  = expf(th_log[s]);
  float mag = expf(-nu);
  lr = mag * cosf(th);
  li = mag * sinf(th);
}

// ---------------------------------------------------------------------------
// MFMA GEMM (Bu and y only): 64x128 tile, 4 waves, BK=32, 2-deep ring,
// counted vmcnt, T2 source-swizzle (conflicts 0), XCD swizzle, LDS-repack
// epilogue with DENSE b128 stores (R9).
// FLAGS: 1=bias 2=+res 4=+dscale[n]*res 8=CHUNK-CARRY (Bu epilogue scan).
// ---------------------------------------------------------------------------
#define RPSTR 136

template<int ACT, int FLAGS>
__global__ __launch_bounds__(256, 6) void mfma_gemm(
    int aSel, int lda, int wSel, int wOff, int ldw,
    int oSel, int ldc,
    const float* __restrict__ bias,
    int rSel, int ldres,
    const float* __restrict__ dscale,
    int K,
    const float* __restrict__ nu_log,
    const float* __restrict__ th_log)
{
  const bf16* A = bufb(aSel);
  const bf16* W = bufb(wSel) + wOff;
  bf16* OB = bufb(oSel);
  const bf16* res = (rSel >= 0) ? bufb(rSel) : nullptr;

  __shared__ __align__(16) unsigned short lds[12288];
  unsigned short* As = lds;          // 2 x 2048 shorts
  unsigned short* Ws = lds + 4096;   // 2 x 4096 shorts

  const int gx = gridDim.x;
  const int nwg = gx * gridDim.y;
  const int orig = blockIdx.y * gx + blockIdx.x;
  const int q = nwg >> 3, r = nwg & 7;
  const int xcd = orig & 7, idx = orig >> 3;
  const int wg = (xcd < r ? xcd*(q+1) : r*(q+1) + (xcd-r)*q) + idx;
  const int bx = wg % gx, by = wg / gx;

  const int tid  = threadIdx.x;
  const int row0 = by * 64, col0 = bx * 128;
  const int lane = tid & 63;
  const int m16  = lane & 15, quad = lane >> 4;
  const int wv   = tid >> 6;
  const int wm   = (wv & 1) * 32, wn = (wv >> 1) * 64;

  const int rlo = wv*16 + (lane >> 2);
  const int sg  = ((lane & 3) ^ ((rlo >> 1) & 3)) * 8;    // shorts
  const bf16* ga = &A[(size_t)(row0 + rlo)*lda + sg];
  const bf16* gw = &W[(size_t)(col0 + rlo)*ldw + sg];
  const size_t w64 = (size_t)64 * ldw;

  auto STAGE = [&](int bb, int k0){
    unsigned short* Ab = As + bb*2048;
    unsigned short* Wb = Ws + bb*4096;
    gld_lds16(ga + k0,       Ab + wv*512);
    gld_lds16(gw + k0,       Wb + wv*512);
    gld_lds16(gw + k0 + w64, Wb + 2048 + wv*512);
  };

  f32x4 acc[2][4] = {};
  const int nt = K >> 5;

  STAGE(0, 0); STAGE(1, 32);

  for (int t = 0; t < nt; ++t){
    const int b = t & 1;
    if (t + 1 < nt) asm volatile("s_waitcnt vmcnt(3)" ::: "memory");
    else            asm volatile("s_waitcnt vmcnt(0)" ::: "memory");
    __builtin_amdgcn_s_barrier();

    const unsigned short* Ab = As + b*2048;
    const unsigned short* Wb = Ws + b*4096;
    bf16x8 af[2], wf[4];
    #pragma unroll
    for (int i = 0; i < 2; i++){
      const int rA = wm + 16*i + m16;
      af[i] = *reinterpret_cast<const bf16x8*>(&Ab[rA*32 + ((quad ^ ((rA>>1)&3))<<3)]);
    }
    #pragma unroll
    for (int j = 0; j < 4; j++){
      const int rW = wn + 16*j + m16;
      wf[j] = *reinterpret_cast<const bf16x8*>(&Wb[rW*32 + ((quad ^ ((rW>>1)&3))<<3)]);
    }
    asm volatile("s_waitcnt lgkmcnt(0)" ::: "memory");
    __builtin_amdgcn_sched_barrier(0);
    __builtin_amdgcn_s_barrier();

    if (t + 2 < nt) STAGE(b, (t + 2) << 5);

    __builtin_amdgcn_s_setprio(1);
    #pragma unroll
    for (int i = 0; i < 2; i++)
      #pragma unroll
      for (int j = 0; j < 4; j++)
        acc[i][j] = __builtin_amdgcn_mfma_f32_16x16x32_bf16(af[i], wf[j], acc[i][j], 0, 0, 0);
    __builtin_amdgcn_s_setprio(0);
  }

  // epilogue phase 1: activate + write padded LDS tile
  #pragma unroll
  for (int i = 0; i < 2; i++){
    #pragma unroll
    for (int j = 0; j < 4; j++){
      const int lcol = wn + 16*j + m16;
      const int col  = col0 + lcol;
      #pragma unroll
      for (int r2 = 0; r2 < 4; r2++){
        const int lrow = wm + 16*i + quad*4 + r2;
        const int row  = row0 + lrow;
        float v = acc[i][j][r2];
        if (FLAGS & 1) v += bias[col];
        if (ACT == 1)  v = fast_gelu(v);
        if (FLAGS & 2) v += __bfloat162float(res[(size_t)row*ldres + col]);
        if (FLAGS & 4) v += dscale[col] * __bfloat162float(res[(size_t)row*ldres + col]);
        bf16 bv = __float2bfloat16(v);
        lds[lrow*RPSTR + lcol] = *reinterpret_cast<unsigned short*>(&bv);
      }
    }
  }
  __syncthreads();

  // epilogue phase 2: DENSE coalesced b128 stores
  {
    const int rr  = tid >> 4;
    const int c16 = (tid & 15) * 8;
    #pragma unroll
    for (int s = 0; s < 4; s++){
      const int orow = s*16 + rr;
      uint4 d = *reinterpret_cast<const uint4*>(&lds[orow*RPSTR + c16]);
      *reinterpret_cast<uint4*>(OB + (size_t)(row0 + orow)*ldc + col0 + c16) = d;
    }
  }

  // epilogue phase 3 (Bu only): chunk-carry scan over the LDS tile
  if (FLAGS & 8){
    if (tid < 64){
      const int sglob = (col0 >> 1) + tid;
      float lr, li; lam_of(nu_log, th_log, sglob, lr, li);
      float ar = 0.f, ai = 0.f;
      for (int t = 0; t < CHUNK; t++){
        unsigned int pr = *reinterpret_cast<const unsigned int*>(&lds[t*RPSTR + 2*tid]);
        float br = __uint_as_float(pr << 16);
        float bi = __uint_as_float(pr & 0xffff0000u);
        float nr = fmaf(lr, ar, fmaf(-li, ai, br));
        float ni = fmaf(lr, ai, fmaf( li, ar, bi));
        ar = nr; ai = ni;
      }
      g_carry[(size_t)by*512 + 2*sglob]     = ar;
      g_carry[(size_t)by*512 + 2*sglob + 1] = ai;
    }
  }
}

// ---------------------------------------------------------------------------
// FUSED MLP (R12): same fusion as R11 (no g_zb), but 512 threads / 8 waves
// per 64-token block. R11 counters showed the kernel GRID-bound at 8 waves/CU
// (512 blocks x 4 waves / 256 CU), Occupancy 21.7%, MfmaUtil 13% — pure
// latency regime (R5-R7 lesson: resident waves are the lever). 8 waves/block
// at unchanged 56.5 KB LDS -> 2 blocks/CU x 8 = 16 waves/CU, weight-staging
// L2 traffic unchanged (still 512 blocks).
// Wave tiles: phase A = 16 tokens x 64 z-cols (af x1, wf x4); phase B =
// 16 tokens x 128 h-cols (wf x8). A-tile staged duplicated across wave pairs
// (benign identical writes); W-tiles exactly covered by 8 waves.
// Raw barriers (lgkm0 only, no vmcnt drain) around zbuf handoffs keep the
// phase-B weight prefetch in flight under the gelu epilogue.
// ---------------------------------------------------------------------------
__global__ __launch_bounds__(512, 4) void fused_mlp(
    int whOff, int woOff,
    const float* __restrict__ bh, const float* __restrict__ bo)
{
  const bf16* Wh = g_Whb + whOff;
  const bf16* Wo = g_Wob + woOff;

  __shared__ __align__(16) unsigned short As[2*2048];    // y ring (8 KB)
  __shared__ __align__(16) unsigned short Ws[2*8192];    // Wh(8KB used)/Wo(16KB) ring (32 KB)
  __shared__ __align__(16) unsigned short zbuf[64*132];  // z_sub / h repack (16.5 KB)

  const int tid  = threadIdx.x;
  const int row0 = blockIdx.x * 64;
  const int lane = tid & 63;
  const int m16  = lane & 15, quad = lane >> 4;
  const int wv   = tid >> 6;             // 0..7
  const int wm   = (wv & 3) * 16;        // 16-token row group
  const int wnA  = (wv >> 2) * 64;       // phase A z-col group
  const int wnB  = (wv >> 2) * 128;      // phase B h-col group

  const int lsub = lane >> 2;            // 0..15
  const int rloA = (wv & 3) * 16 + lsub;         // 0..63 (dup across wv>>2)
  const int sgA  = ((lane & 3) ^ ((rloA >> 1) & 3)) * 8;
  const int rloW = wv * 16 + lsub;               // 0..127
  const int sgW  = ((lane & 3) ^ ((rloW >> 1) & 3)) * 8;

  const bf16* ga = g_yb + (size_t)(row0 + rloA)*HIDD + sgA;

  f32x4 accB[8] = {};

  for (int mc = 0; mc < 8; ++mc){
    const bf16* gwh = Wh + (size_t)(mc*128 + rloW)*HIDD + sgW;

    auto STAGE_A = [&](int b, int k0){
      gld_lds16(ga + k0,  As + b*2048 + (wv & 3)*512);   // dup-write ok
      gld_lds16(gwh + k0, Ws + b*8192 + wv*512);
    };
    auto STAGE_B = [&](int b, int ks){
      #pragma unroll
      for (int g = 0; g < 2; g++)
        gld_lds16(Wo + (size_t)(g*128 + rloW)*MLPD + mc*128 + ks*32 + sgW,
                  Ws + b*8192 + g*4096 + wv*512);
    };

    // ---- phase A: z_sub = gelu(y @ Wh_sub^T + bh), K=256 ----
    f32x4 accA[4] = {};
    STAGE_A(0, 0); STAGE_A(1, 32);       // 4 loads/wave in flight
    for (int t = 0; t < 8; ++t){
      const int b = t & 1;
      if (t + 1 < 8) asm volatile("s_waitcnt vmcnt(2)" ::: "memory");
      else           asm volatile("s_waitcnt vmcnt(0)" ::: "memory");
      __builtin_amdgcn_s_barrier();
      const unsigned short* Ab = As + b*2048;
      const unsigned short* Wb = Ws + b*8192;
      bf16x8 af, wf[4];
      { const int rA = wm + m16;
        af = *reinterpret_cast<const bf16x8*>(&Ab[rA*32 + ((quad ^ ((rA>>1)&3))<<3)]); }
      #pragma unroll
      for (int j = 0; j < 4; j++){
        const int rW = wnA + 16*j + m16;
        wf[j] = *reinterpret_cast<const bf16x8*>(&Wb[rW*32 + ((quad ^ ((rW>>1)&3))<<3)]);
      }
      asm volatile("s_waitcnt lgkmcnt(0)" ::: "memory");
      __builtin_amdgcn_sched_barrier(0);
      __builtin_amdgcn_s_barrier();
      if (t + 2 < 8) STAGE_A(b, (t + 2) << 5);
      __builtin_amdgcn_s_setprio(1);
      #pragma unroll
      for (int j = 0; j < 4; j++)
        accA[j] = __builtin_amdgcn_mfma_f32_16x16x32_bf16(af, wf[j], accA[j], 0, 0, 0);
      __builtin_amdgcn_s_setprio(0);
    }

    // prefetch phase-B weight tiles; latency hides under gelu epilogue
    STAGE_B(0, 0); STAGE_B(1, 1);

    // epilogue A: bias + gelu -> zbuf (no global write)
    #pragma unroll
    for (int j = 0; j < 4; j++){
      const int lcol = wnA + 16*j + m16;
      const float bb = bh[mc*128 + lcol];
      #pragma unroll
      for (int r2 = 0; r2 < 4; r2++){
        const int lrow = wm + quad*4 + r2;
        float v = fast_gelu(accA[j][r2] + bb);
        bf16 bv = __float2bfloat16(v);
        zbuf[lrow*132 + lcol] = *reinterpret_cast<unsigned short*>(&bv);
      }
    }
    // raw barrier (NO vmcnt drain — B prefetch stays in flight)
    asm volatile("s_waitcnt lgkmcnt(0)" ::: "memory");
    __builtin_amdgcn_sched_barrier(0);
    __builtin_amdgcn_s_barrier();
    __builtin_amdgcn_sched_barrier(0);

    // ---- phase B: accB += z_sub @ Wo_sub^T, K=128 ----
    for (int ks = 0; ks < 4; ++ks){
      const int b = ks & 1;
      if (ks + 1 < 4) asm volatile("s_waitcnt vmcnt(2)" ::: "memory");
      else            asm volatile("s_waitcnt vmcnt(0)" ::: "memory");
      __builtin_amdgcn_s_barrier();
      const unsigned short* Wb = Ws + b*8192;
      bf16x8 af, wf[8];
      { const int rA = wm + m16;
        af = *reinterpret_cast<const bf16x8*>(&zbuf[rA*132 + ks*32 + quad*8]); }
      #pragma unroll
      for (int j = 0; j < 8; j++){
        const int rW = wnB + 16*j + m16;
        wf[j] = *reinterpret_cast<const bf16x8*>(&Wb[rW*32 + ((quad ^ ((rW>>1)&3))<<3)]);
      }
      asm volatile("s_waitcnt lgkmcnt(0)" ::: "memory");
      __builtin_amdgcn_sched_barrier(0);
      __builtin_amdgcn_s_barrier();
      if (ks + 2 < 4) STAGE_B(b, ks + 2);
      __builtin_amdgcn_s_setprio(1);
      #pragma unroll
      for (int j = 0; j < 8; j++)
        accB[j] = __builtin_amdgcn_mfma_f32_16x16x32_bf16(af, wf[j], accB[j], 0, 0, 0);
      __builtin_amdgcn_s_setprio(0);
    }
  }

  // ---- final epilogue: h = accB + bo + y, two col-halves via zbuf ----
  #pragma unroll
  for (int n = 0; n < 2; n++){
    asm volatile("s_waitcnt lgkmcnt(0)" ::: "memory");
    __builtin_amdgcn_sched_barrier(0);
    __builtin_amdgcn_s_barrier();       // prior zbuf reads done (all waves)
    __builtin_amdgcn_sched_barrier(0);
    if ((wv >> 2) == n){
      #pragma unroll
      for (int j = 0; j < 8; j++){
        const int lcol = 16*j + m16;
        const float bb = bo[n*128 + lcol];
        #pragma unroll
        for (int r2 = 0; r2 < 4; r2++){
          const int lrow = wm + quad*4 + r2;
          float v = accB[j][r2] + bb;
          bf16 bv = __float2bfloat16(v);
          zbuf[lrow*132 + lcol] = *reinterpret_cast<unsigned short*>(&bv);
        }
      }
    }
    asm volatile("s_waitcnt lgkmcnt(0)" ::: "memory");
    __builtin_amdgcn_sched_barrier(0);
    __builtin_amdgcn_s_barrier();       // writes visible
    __builtin_amdgcn_sched_barrier(0);
    const int rr = tid >> 4, c16 = (tid & 15) * 8;   // rr 0..31
    #pragma unroll
    for (int s = 0; s < 2; s++){
      const int orow = s*32 + rr;
      uint4 hv = *reinterpret_cast<const uint4*>(&zbuf[orow*132 + c16]);
      const size_t go = (size_t)(row0 + orow)*HIDD + n*128 + c16;
      uint4 yv = *reinterpret_cast<const uint4*>(g_yb + go);
      uint4 o;
      o.x = bf2_add(hv.x, yv.x); o.y = bf2_add(hv.y, yv.y);
      o.z = bf2_add(hv.z, yv.z); o.w = bf2_add(hv.w, yv.w);
      *reinterpret_cast<uint4*>(g_hb + go) = o;
    }
  }
}

// ---------------------------------------------------------------------------
// fp32 tiled GEMMs for the small ends (embed, out) — proven R12 structure.
// ---------------------------------------------------------------------------
__global__ __launch_bounds__(256) void emb_gemm(
    const float* __restrict__ x, const float* __restrict__ W,
    const float* __restrict__ b)
{
  __shared__ __align__(16) float Asx[16][68];
  __shared__ __align__(16) float Wsx[16][68];
  const int tid = threadIdx.x;
  const int tx = tid & 15, ty = tid >> 4;
  const int row0 = blockIdx.y * 64, col0 = blockIdx.x * 64;
  const int lc = tid & 15, lr = tid >> 4;
  float acc[4][4] = {};
  for (int k0 = 0; k0 < INDIM; k0 += 16){
    #pragma unroll
    for (int i = 0; i < 4; i++){
      Asx[lc][lr + 16*i] = x[(size_t)(row0 + lr + 16*i)*INDIM + k0 + lc];
      Wsx[lc][lr + 16*i] = W[(size_t)(col0 + lr + 16*i)*INDIM + k0 + lc];
    }
    __syncthreads();
    #pragma unroll
    for (int k = 0; k < 16; k++){
      float4 av = *reinterpret_cast<const float4*>(&Asx[k][ty*4]);
      float4 bv = *reinterpret_cast<const float4*>(&Wsx[k][tx*4]);
      float a[4] = {av.x, av.y, av.z, av.w};
      float b2[4] = {bv.x, bv.y, bv.z, bv.w};
      #pragma unroll
      for (int i = 0; i < 4; i++)
        #pragma unroll
        for (int j = 0; j < 4; j++)
          acc[i][j] = fmaf(a[i], b2[j], acc[i][j]);
    }
    __syncthreads();
  }
  #pragma unroll
  for (int i = 0; i < 4; i++){
    const int r = row0 + ty*4 + i;
    #pragma unroll
    for (int j = 0; j < 4; j++){
      const int cn = col0 + tx*4 + j;
      g_hb[(size_t)r*HIDD + cn] = __float2bfloat16(acc[i][j] + b[cn]);
    }
  }
}

__global__ __launch_bounds__(256) void out_gemm(
    const float* __restrict__ W, const float* __restrict__ b,
    float* __restrict__ out)
{
  __shared__ __align__(16) float Asx[16][68];
  __shared__ __align__(16) float Wsx[16][68];
  const int tid = threadIdx.x;
  const int tx = tid & 15, ty = tid >> 4;
  const int row0 = blockIdx.y * 64, col0 = blockIdx.x * 64;
  const int lc = tid & 15, lr = tid >> 4;
  float acc[4][4] = {};
  for (int k0 = 0; k0 < HIDD; k0 += 16){
    #pragma unroll
    for (int i = 0; i < 4; i++){
      Asx[lc][lr + 16*i] = __bfloat162float(g_hb[(size_t)(row0 + lr + 16*i)*HIDD + k0 + lc]);
      Wsx[lc][lr + 16*i] = W[(size_t)(col0 + lr + 16*i)*HIDD + k0 + lc];
    }
    __syncthreads();
    #pragma unroll
    for (int k = 0; k < 16; k++){
      float4 av = *reinterpret_cast<const float4*>(&Asx[k][ty*4]);
      float4 bv = *reinterpret_cast<const float4*>(&Wsx[k][tx*4]);
      float a[4] = {av.x, av.y, av.z, av.w};
      float b2[4] = {bv.x, bv.y, bv.z, bv.w};
      #pragma unroll
      for (int i = 0; i < 4; i++)
        #pragma unroll
        for (int j = 0; j < 4; j++)
          acc[i][j] = fmaf(a[i], b2[j], acc[i][j]);
    }
    __syncthreads();
  }
  #pragma unroll
  for (int i = 0; i < 4; i++){
    const int r = row0 + ty*4 + i;
    #pragma unroll
    for (int j = 0; j < 4; j++){
      const int cn = col0 + tx*4 + j;
      out[(size_t)r*OUTD + cn] = acc[i][j] + b[cn];
    }
  }
}

// ---------------------------------------------------------------------------
// Prefix accumulate over chunk carries + local re-scan seeded with prefix.
// Interleaved layout: thread s owns complex state s at uint-paired cols.
// ---------------------------------------------------------------------------
__global__ __launch_bounds__(256) void scan_fix(
    const float* __restrict__ nu_log, const float* __restrict__ th_log)
{
  const int blk = blockIdx.x;
  const int c   = blk & (NCHUNK - 1);
  const int s   = threadIdx.x;
  float lr, li; lam_of(nu_log, th_log, s, lr, li);
  float cr = 0.f, ci = 0.f;
  if (c > 0){
    float Tr = lr, Ti = li;
    #pragma unroll
    for (int i = 0; i < 6; i++){ float nr = Tr*Tr - Ti*Ti; Ti = 2.f*Tr*Ti; Tr = nr; }
    const int bstart = blk - c;
    for (int j = 0; j < c; j++){
      float2 e = *reinterpret_cast<const float2*>(&g_carry[(size_t)(bstart + j)*512 + 2*s]);
      float nr = fmaf(Tr, cr, fmaf(-Ti, ci, e.x));
      float ni = fmaf(Tr, ci, fmaf( Ti, cr, e.y));
      cr = nr; ci = ni;
    }
  }
  float ar = cr, ai = ci;
  unsigned int* pb = reinterpret_cast<unsigned int*>(g_bub) + (size_t)blk*CHUNK*256 + s;
  for (int t = 0; t < CHUNK; t++){
    unsigned int pr = pb[(size_t)t*256];
    float br = __uint_as_float(pr << 16);
    float bi = __uint_as_float(pr & 0xffff0000u);
    float nr = fmaf(lr, ar, fmaf(-li, ai, br));
    float ni = fmaf(lr, ai, fmaf( li, ar, bi));
    ar = nr; ai = ni;
    bf16 hr = __float2bfloat16(ar), hi2 = __float2bfloat16(ai);
    unsigned int w = (unsigned int)(*reinterpret_cast<unsigned short*>(&hr))
                   | ((unsigned int)(*reinterpret_cast<unsigned short*>(&hi2)) << 16);
    pb[(size_t)t*256] = w;
  }
}

// Pack B_norm for ALL layers -> bf16, rows INTERLEAVED: row 2s=re_s, 2s+1=im_s
__global__ __launch_bounds__(256) void pack_B(
    const float* __restrict__ Bre, const float* __restrict__ Bim,
    const float* __restrict__ gl)
{
  int idx = blockIdx.x * 256 + threadIdx.x;
  int l = idx >> 16, within = idx & 65535;
  int s = within >> 8, h = within & 255;
  float g = expf(gl[l*STATE_D + s]);
  g_Bnb[(size_t)l*131072 + (size_t)(2*s  )*256 + h] = __float2bfloat16(Bre[idx] * g);
  g_Bnb[(size_t)l*131072 + (size_t)(2*s+1)*256 + h] = __float2bfloat16(Bim[idx] * g);
}

// Pack Cw for ALL layers -> bf16, cols INTERLEAVED: col 2s=Cre, 2s+1=-Cim
__global__ __launch_bounds__(256) void pack_C(
    const float* __restrict__ Cre, const float* __restrict__ Cim)
{
  int idx = blockIdx.x * 256 + threadIdx.x;
  int l = idx >> 16, within = idx & 65535;
  int h = within >> 8, s = within & 255;
  g_Cwb[(size_t)l*131072 + (size_t)h*512 + 2*s]     = __float2bfloat16( Cre[idx]);
  g_Cwb[(size_t)l*131072 + (size_t)h*512 + 2*s + 1] = __float2bfloat16(-Cim[idx]);
}

// Straight fp32 -> bf16 weight convert into selected buffer
__global__ __launch_bounds__(256) void conv_bf16(
    const float* __restrict__ src, int dstSel, int n)
{
  int i = blockIdx.x * 256 + threadIdx.x;
  if (i < n) bufb(dstSel)[i] = __float2bfloat16(src[i]);
}

// ---------------------------------------------------------------------------
extern "C" void kernel_launch(void* const* d_in, const int* in_sizes, int n_in,
                              void* d_out, int out_size, void* d_ws, size_t ws_size,
                              hipStream_t stream)
{
  (void)d_ws; (void)ws_size; (void)out_size; (void)n_in; (void)in_sizes;
  const float* x      = (const float*)d_in[0];
  const float* emb_W  = (const float*)d_in[1];
  const float* emb_b  = (const float*)d_in[2];
  const float* nu_log = (const float*)d_in[3];
  const float* th_log = (const float*)d_in[4];
  const float* ga_log = (const float*)d_in[5];
  const float* B_re   = (const float*)d_in[6];
  const float* B_im   = (const float*)d_in[7];
  const float* C_re   = (const float*)d_in[8];
  const float* C_im   = (const float*)d_in[9];
  const float* Dv     = (const float*)d_in[10];
  const float* Wh     = (const float*)d_in[11];
  const float* bh     = (const float*)d_in[12];
  const float* Wo     = (const float*)d_in[13];
  const float* bo     = (const float*)d_in[14];
  const float* out_W  = (const float*)d_in[15];
  const float* out_b  = (const float*)d_in[16];

  const dim3 blk(256);

  // ---- all weight packing upfront ----
  pack_B<<<dim3(NLAYERS*256), blk, 0, stream>>>(B_re, B_im, ga_log);
  pack_C<<<dim3(NLAYERS*256), blk, 0, stream>>>(C_re, C_im);
  conv_bf16<<<dim3(NLAYERS*1024), blk, 0, stream>>>(Wh, SB_WHB, NLAYERS*262144);
  conv_bf16<<<dim3(NLAYERS*1024), blk, 0, stream>>>(Wo, SB_WOB, NLAYERS*262144);

  // embed: h = x @ emb_W^T + emb_b  -> g_hb
  emb_gemm<<<dim3(HIDD/64, M_TOK/64), blk, 0, stream>>>(x, emb_W, emb_b);

  for (int l = 0; l < NLAYERS; l++){
    // Bu = h @ Bn^T (32768 x 512 x 256) -> g_bub bf16 + chunk carries
    mfma_gemm<0, 8><<<dim3(4, M_TOK/64), blk, 0, stream>>>(
        SB_HB, HIDD, SB_BNB, l*131072, HIDD, SB_BUB, 512,
        nullptr, -1, 0, nullptr, HIDD,
        nu_log + l*STATE_D, th_log + l*STATE_D);

    // prefix + rescan (in-place states)
    scan_fix<<<dim3(M_TOK/CHUNK), blk, 0, stream>>>(nu_log + l*STATE_D, th_log + l*STATE_D);

    // y = states @ Cw^T + D*h -> g_yb
    mfma_gemm<0, 4><<<dim3(2, M_TOK/64), blk, 0, stream>>>(
        SB_BUB, 512, SB_CWB, l*131072, 512, SB_YB, HIDD,
        nullptr, SB_HB, HIDD, Dv + l*HIDD, 512, nullptr, nullptr);

    // h = gelu(y @ Wh^T + bh) @ Wo^T + bo + y  (fused, 8-wave blocks)
    fused_mlp<<<dim3(M_TOK/64), dim3(512), 0, stream>>>(
        l*262144, l*262144, bh + l*MLPD, bo + l*HIDD);
  }

  // out = h @ out_W^T + out_b
  out_gemm<<<dim3(OUTD/64, M_TOK/64), blk, 0, stream>>>(out_W, out_b, (float*)d_out);
}

// Round 13
// 711.033 us; speedup vs baseline: 1.0797x; 1.0797x over previous
//
#include <hip/hip_runtime.h>
#include <hip/hip_bf16.h>
#include <math.h>

typedef __hip_bfloat16 bf16;
typedef __attribute__((ext_vector_type(8))) short bf16x8;   // 8 bf16 = 4 VGPR
typedef __attribute__((ext_vector_type(4))) float f32x4;    // MFMA acc

#define BATCH   16
#define SEQLEN  2048
#define INDIM   64
#define HIDD    256
#define STATE_D 256
#define MLPD    1024
#define OUTD    128
#define NLAYERS 4
#define M_TOK   (BATCH*SEQLEN)     // 32768 tokens
#define CHUNK   64
#define NCHUNK  (SEQLEN/CHUNK)     // 32 chunks per batch

// ---- ALL-BF16 activation chain; complex-interleaved states (R10) ---------
__device__ float g_carry[512*512];          // fp32 carries [chunk][2s|2s+1]
__device__ bf16  g_hb [(size_t)M_TOK*256];
__device__ bf16  g_yb [(size_t)M_TOK*256];
__device__ bf16  g_bub[(size_t)M_TOK*512];  // raw Bu, then scan states (in place)
// per-layer packed weights (hoisted out of the layer loop)
__device__ bf16  g_Bnb[NLAYERS*512*256];    // B_norm rows interleaved: 2s=re, 2s+1=im
__device__ bf16  g_Cwb[NLAYERS*256*512];    // cols interleaved: 2s=Cre, 2s+1=-Cim
__device__ bf16  g_Whb[NLAYERS*1024*256];
__device__ bf16  g_Wob[NLAYERS*256*1024];

#define SB_HB  0
#define SB_YB  1
#define SB_BUB 2
#define SB_BNB 4
#define SB_CWB 5
#define SB_WHB 6
#define SB_WOB 7

__device__ __forceinline__ bf16* bufb(int sel){
  switch(sel){
    case SB_HB:  return g_hb;  case SB_YB:  return g_yb;
    case SB_BUB: return g_bub;
    case SB_BNB: return g_Bnb; case SB_CWB: return g_Cwb;
    case SB_WHB: return g_Whb; default:     return g_Wob; }
}

// async global->LDS, 16B per lane. LDS dest is wave-uniform base + lane*16.
__device__ __forceinline__ void gld_lds16(const void* g, void* l){
  __builtin_amdgcn_global_load_lds(
      (const __attribute__((address_space(1))) unsigned int*)g,
      (__attribute__((address_space(3))) unsigned int*)l, 16, 0, 0);
}

// Branch-free exact-GELU via Abramowitz-Stegun 7.1.26 erf (|err|<=1.5e-7).
__device__ __forceinline__ float fast_gelu(float v){
  const float x  = v * 0.70710678118654752f;
  const float ax = fabsf(x);
  const float t  = __builtin_amdgcn_rcpf(fmaf(0.3275911f, ax, 1.0f));
  float p = fmaf(t, 1.061405429f, -1.453152027f);
  p = fmaf(t, p, 1.421413741f);
  p = fmaf(t, p, -0.284496736f);
  p = fmaf(t, p, 0.254829592f);
  p = p * t;
  const float e = __expf(-ax * ax);
  const float erf_ax = fmaf(-p, e, 1.0f);
  const float erf_x  = copysignf(erf_ax, x);
  return 0.5f * v * (1.0f + erf_x);
}

// pairwise add of 2 packed bf16 lanes in fp32, repack to bf16
__device__ __forceinline__ unsigned int bf2_add(unsigned int a, unsigned int b){
  float alo = __uint_as_float(a << 16), ahi = __uint_as_float(a & 0xffff0000u);
  float blo = __uint_as_float(b << 16), bhi = __uint_as_float(b & 0xffff0000u);
  bf16 l = __float2bfloat16(alo + blo);
  bf16 h = __float2bfloat16(ahi + bhi);
  return (unsigned int)(*reinterpret_cast<unsigned short*>(&l))
       | ((unsigned int)(*reinterpret_cast<unsigned short*>(&h)) << 16);
}

// lam_s = exp(-exp(nu)) * (cos(exp(th)) + i sin(exp(th)))
__device__ __forceinline__ void lam_of(const float* __restrict__ nu_log,
                                       const float* __restrict__ th_log,
                                       int s, float& lr, float& li)
{
  float nu  = expf(nu_log[s]);
  float th  = expf(th_log[s]);
  float mag = expf(-nu);
  lr = mag * cosf(th);
  li = mag * sinf(th);
}

// ---------------------------------------------------------------------------
// MFMA GEMM (Bu and y): 64x128 tile, 4 waves, BK=32.
// R13: SINGLE-BARRIER 3-ring K-loop. Ledger: at iter t's barrier, (a) each
// wave has vmcnt-waited its OWN tile-t loads -> tile t resident everywhere;
// (b) every wave lgkm0'd its iter-(t-1) reads of buf (t+2)%3 before arriving
// -> that buffer is free to restage. Order per iter:
//   vmcnt(3|0) -> s_barrier -> STAGE(t+2 -> buf (t+2)%3) -> ds_read(buf t%3)
//   -> lgkm0 -> MFMA.
// One extra barrier post-loop guards the LDS repack against other waves'
// final ds_reads. Halves barrier count vs R6 discipline (2/iter -> 1/iter).
// LDS 36 KB -> 4 blocks/CU x 4 waves = 16 waves/CU (same residency as R12's
// 24 KB/6-block config; measured occupancy was ~51% = 16 waves).
// FLAGS: 1=bias 2=+res 4=+dscale[n]*res 8=CHUNK-CARRY (Bu epilogue scan).
// ---------------------------------------------------------------------------
#define RPSTR 136

template<int ACT, int FLAGS>
__global__ __launch_bounds__(256, 4) void mfma_gemm(
    int aSel, int lda, int wSel, int wOff, int ldw,
    int oSel, int ldc,
    const float* __restrict__ bias,
    int rSel, int ldres,
    const float* __restrict__ dscale,
    int K,
    const float* __restrict__ nu_log,
    const float* __restrict__ th_log)
{
  const bf16* A = bufb(aSel);
  const bf16* W = bufb(wSel) + wOff;
  bf16* OB = bufb(oSel);
  const bf16* res = (rSel >= 0) ? bufb(rSel) : nullptr;

  __shared__ __align__(16) unsigned short lds[18432];   // 36 KB: 3-ring
  unsigned short* As = lds;            // 3 x 2048 shorts
  unsigned short* Ws = lds + 6144;     // 3 x 4096 shorts

  const int gx = gridDim.x;
  const int nwg = gx * gridDim.y;
  const int orig = blockIdx.y * gx + blockIdx.x;
  const int q = nwg >> 3, r = nwg & 7;
  const int xcd = orig & 7, idx = orig >> 3;
  const int wg = (xcd < r ? xcd*(q+1) : r*(q+1) + (xcd-r)*q) + idx;
  const int bx = wg % gx, by = wg / gx;

  const int tid  = threadIdx.x;
  const int row0 = by * 64, col0 = bx * 128;
  const int lane = tid & 63;
  const int m16  = lane & 15, quad = lane >> 4;
  const int wv   = tid >> 6;
  const int wm   = (wv & 1) * 32, wn = (wv >> 1) * 64;

  const int rlo = wv*16 + (lane >> 2);
  const int sg  = ((lane & 3) ^ ((rlo >> 1) & 3)) * 8;    // shorts
  const bf16* ga = &A[(size_t)(row0 + rlo)*lda + sg];
  const bf16* gw = &W[(size_t)(col0 + rlo)*ldw + sg];
  const size_t w64 = (size_t)64 * ldw;

  auto STAGE = [&](int bb, int k0){
    unsigned short* Ab = As + bb*2048;
    unsigned short* Wb = Ws + bb*4096;
    gld_lds16(ga + k0,       Ab + wv*512);
    gld_lds16(gw + k0,       Wb + wv*512);
    gld_lds16(gw + k0 + w64, Wb + 2048 + wv*512);
  };

  f32x4 acc[2][4] = {};
  const int nt = K >> 5;

  STAGE(0, 0); STAGE(1, 32);

  int b = 0;
  for (int t = 0; t < nt; ++t){
    if (t + 1 < nt) asm volatile("s_waitcnt vmcnt(3)" ::: "memory");
    else            asm volatile("s_waitcnt vmcnt(0)" ::: "memory");
    __builtin_amdgcn_s_barrier();    // tile t resident; buf (t+2)%3 free

    if (t + 2 < nt){
      const int st = (b == 0) ? 2 : b - 1;   // (t+2)%3
      STAGE(st, (t + 2) << 5);
    }

    const unsigned short* Ab = As + b*2048;
    const unsigned short* Wb = Ws + b*4096;
    bf16x8 af[2], wf[4];
    #pragma unroll
    for (int i = 0; i < 2; i++){
      const int rA = wm + 16*i + m16;
      af[i] = *reinterpret_cast<const bf16x8*>(&Ab[rA*32 + ((quad ^ ((rA>>1)&3))<<3)]);
    }
    #pragma unroll
    for (int j = 0; j < 4; j++){
      const int rW = wn + 16*j + m16;
      wf[j] = *reinterpret_cast<const bf16x8*>(&Wb[rW*32 + ((quad ^ ((rW>>1)&3))<<3)]);
    }
    asm volatile("s_waitcnt lgkmcnt(0)" ::: "memory");
    __builtin_amdgcn_sched_barrier(0);

    __builtin_amdgcn_s_setprio(1);
    #pragma unroll
    for (int i = 0; i < 2; i++)
      #pragma unroll
      for (int j = 0; j < 4; j++)
        acc[i][j] = __builtin_amdgcn_mfma_f32_16x16x32_bf16(af[i], wf[j], acc[i][j], 0, 0, 0);
    __builtin_amdgcn_s_setprio(0);

    b = (b == 2) ? 0 : b + 1;
  }
  __builtin_amdgcn_s_barrier();   // all waves' final ds_reads done -> repack may overwrite lds

  // epilogue phase 1: activate + write padded LDS tile
  #pragma unroll
  for (int i = 0; i < 2; i++){
    #pragma unroll
    for (int j = 0; j < 4; j++){
      const int lcol = wn + 16*j + m16;
      const int col  = col0 + lcol;
      #pragma unroll
      for (int r2 = 0; r2 < 4; r2++){
        const int lrow = wm + 16*i + quad*4 + r2;
        const int row  = row0 + lrow;
        float v = acc[i][j][r2];
        if (FLAGS & 1) v += bias[col];
        if (ACT == 1)  v = fast_gelu(v);
        if (FLAGS & 2) v += __bfloat162float(res[(size_t)row*ldres + col]);
        if (FLAGS & 4) v += dscale[col] * __bfloat162float(res[(size_t)row*ldres + col]);
        bf16 bv = __float2bfloat16(v);
        lds[lrow*RPSTR + lcol] = *reinterpret_cast<unsigned short*>(&bv);
      }
    }
  }
  __syncthreads();

  // epilogue phase 2: DENSE coalesced b128 stores (R9)
  {
    const int rr  = tid >> 4;
    const int c16 = (tid & 15) * 8;
    #pragma unroll
    for (int s = 0; s < 4; s++){
      const int orow = s*16 + rr;
      uint4 d = *reinterpret_cast<const uint4*>(&lds[orow*RPSTR + c16]);
      *reinterpret_cast<uint4*>(OB + (size_t)(row0 + orow)*ldc + col0 + c16) = d;
    }
  }

  // epilogue phase 3 (Bu only): chunk-carry scan over the LDS tile (R10)
  if (FLAGS & 8){
    if (tid < 64){
      const int sglob = (col0 >> 1) + tid;
      float lr, li; lam_of(nu_log, th_log, sglob, lr, li);
      float ar = 0.f, ai = 0.f;
      for (int t = 0; t < CHUNK; t++){
        unsigned int pr = *reinterpret_cast<const unsigned int*>(&lds[t*RPSTR + 2*tid]);
        float br = __uint_as_float(pr << 16);
        float bi = __uint_as_float(pr & 0xffff0000u);
        float nr = fmaf(lr, ar, fmaf(-li, ai, br));
        float ni = fmaf(lr, ai, fmaf( li, ar, bi));
        ar = nr; ai = ni;
      }
      g_carry[(size_t)by*512 + 2*sglob]     = ar;
      g_carry[(size_t)by*512 + 2*sglob + 1] = ai;
    }
  }
}

// ---------------------------------------------------------------------------
// FUSED MLP (R13): R12's 512-thread fusion with SINGLE-BARRIER 3-ring in
// both phases (same ledger as mfma_gemm). Per mc: phase A 8 iters (1 barrier
// each), B-prefetch into the two certified-free Ws buffers pre-gelu, one
// post-gelu raw barrier, phase B 4 iters (1 barrier each). Barriers/mc
// ~25 -> ~13. LDS: As 3x4KB + Ws 3x16KB + zbuf 16.5KB = 76.5 KB -> 2
// blocks/CU x 8 waves = 16 waves/CU.
// Phase-B ring: iter ks reads Ws buf (ks+2)%3, stages tile ks+2 into buf
// (ks+1)%3 (free: its phase-A reads certified by post-gelu + iter barriers).
// mc->mc+1 handoff: prologue stages Ws bufs 0,1 (reads certified by B-iter
// 2,3 barriers); phase-A iter0 stages buf2 (B-iter-3 reads certified by its
// barrier).
// ---------------------------------------------------------------------------
__global__ __launch_bounds__(512, 4) void fused_mlp(
    int whOff, int woOff,
    const float* __restrict__ bh, const float* __restrict__ bo)
{
  const bf16* Wh = g_Whb + whOff;
  const bf16* Wo = g_Wob + woOff;

  __shared__ __align__(16) unsigned short As[3*2048];    // y ring (12 KB)
  __shared__ __align__(16) unsigned short Ws[3*8192];    // Wh/Wo ring (48 KB)
  __shared__ __align__(16) unsigned short zbuf[64*132];  // z_sub / h repack (16.5 KB)

  const int tid  = threadIdx.x;
  const int row0 = blockIdx.x * 64;
  const int lane = tid & 63;
  const int m16  = lane & 15, quad = lane >> 4;
  const int wv   = tid >> 6;             // 0..7
  const int wm   = (wv & 3) * 16;        // 16-token row group
  const int wnA  = (wv >> 2) * 64;       // phase A z-col group
  const int wnB  = (wv >> 2) * 128;      // phase B h-col group

  const int lsub = lane >> 2;            // 0..15
  const int rloA = (wv & 3) * 16 + lsub;         // 0..63 (dup across wv>>2)
  const int sgA  = ((lane & 3) ^ ((rloA >> 1) & 3)) * 8;
  const int rloW = wv * 16 + lsub;               // 0..127
  const int sgW  = ((lane & 3) ^ ((rloW >> 1) & 3)) * 8;

  const bf16* ga = g_yb + (size_t)(row0 + rloA)*HIDD + sgA;

  f32x4 accB[8] = {};

  for (int mc = 0; mc < 8; ++mc){
    const bf16* gwh = Wh + (size_t)(mc*128 + rloW)*HIDD + sgW;

    auto STAGE_A = [&](int b, int k0){
      gld_lds16(ga + k0,  As + b*2048 + (wv & 3)*512);   // dup-write ok
      gld_lds16(gwh + k0, Ws + b*8192 + wv*512);
    };
    auto STAGE_B = [&](int b, int ks){
      #pragma unroll
      for (int g = 0; g < 2; g++)
        gld_lds16(Wo + (size_t)(g*128 + rloW)*MLPD + mc*128 + ks*32 + sgW,
                  Ws + b*8192 + g*4096 + wv*512);
    };

    // ---- phase A: z_sub = gelu(y @ Wh_sub^T + bh), K=256, 1 barrier/iter ----
    f32x4 accA[4] = {};
    STAGE_A(0, 0); STAGE_A(1, 32);       // 4 loads/wave in flight
    int b = 0;
    for (int t = 0; t < 8; ++t){
      if (t + 1 < 8) asm volatile("s_waitcnt vmcnt(2)" ::: "memory");
      else           asm volatile("s_waitcnt vmcnt(0)" ::: "memory");
      __builtin_amdgcn_s_barrier();      // tile t resident; buf (t+2)%3 free
      if (t + 2 < 8){
        const int st = (b == 0) ? 2 : b - 1;
        STAGE_A(st, (t + 2) << 5);
      }
      const unsigned short* Ab = As + b*2048;
      const unsigned short* Wb = Ws + b*8192;
      bf16x8 af, wf[4];
      { const int rA = wm + m16;
        af = *reinterpret_cast<const bf16x8*>(&Ab[rA*32 + ((quad ^ ((rA>>1)&3))<<3)]); }
      #pragma unroll
      for (int j = 0; j < 4; j++){
        const int rW = wnA + 16*j + m16;
        wf[j] = *reinterpret_cast<const bf16x8*>(&Wb[rW*32 + ((quad ^ ((rW>>1)&3))<<3)]);
      }
      asm volatile("s_waitcnt lgkmcnt(0)" ::: "memory");
      __builtin_amdgcn_sched_barrier(0);
      __builtin_amdgcn_s_setprio(1);
      #pragma unroll
      for (int j = 0; j < 4; j++)
        accA[j] = __builtin_amdgcn_mfma_f32_16x16x32_bf16(af, wf[j], accA[j], 0, 0, 0);
      __builtin_amdgcn_s_setprio(0);
      b = (b == 2) ? 0 : b + 1;
    }
    // A-loop read bufs: t6->0 (certified by t7 barrier), t7->1 (NOT yet).
    // Prefetch phase-B tiles into the certified-free bufs 2 and 0; buf 1
    // only after the post-gelu barrier. HBM latency hides under gelu.
    STAGE_B(2, 0); STAGE_B(0, 1);

    // epilogue A: bias + gelu -> zbuf (no global write)
    #pragma unroll
    for (int j = 0; j < 4; j++){
      const int lcol = wnA + 16*j + m16;
      const float bb = bh[mc*128 + lcol];
      #pragma unroll
      for (int r2 = 0; r2 < 4; r2++){
        const int lrow = wm + quad*4 + r2;
        float v = fast_gelu(accA[j][r2] + bb);
        bf16 bv = __float2bfloat16(v);
        zbuf[lrow*132 + lcol] = *reinterpret_cast<unsigned short*>(&bv);
      }
    }
    // raw barrier (NO vmcnt drain — B prefetch stays in flight).
    // Certifies: zbuf writes visible AND everyone's phase-A iter-7 reads done.
    asm volatile("s_waitcnt lgkmcnt(0)" ::: "memory");
    __builtin_amdgcn_sched_barrier(0);
    __builtin_amdgcn_s_barrier();
    __builtin_amdgcn_sched_barrier(0);

    // ---- phase B: accB += z_sub @ Wo_sub^T, K=128, 1 barrier/iter ----
    for (int ks = 0; ks < 4; ++ks){
      const int rb = (ks + 2) % 3;       // read buf: 2,0,1,2
      if (ks + 1 < 4) asm volatile("s_waitcnt vmcnt(2)" ::: "memory");
      else            asm volatile("s_waitcnt vmcnt(0)" ::: "memory");
      __builtin_amdgcn_s_barrier();      // B-tile ks resident; stage target free
      if (ks + 2 < 4) STAGE_B((ks + 1) % 3, ks + 2);
      const unsigned short* Wb = Ws + rb*8192;
      bf16x8 af, wf[8];
      { const int rA = wm + m16;
        af = *reinterpret_cast<const bf16x8*>(&zbuf[rA*132 + ks*32 + quad*8]); }
      #pragma unroll
      for (int j = 0; j < 8; j++){
        const int rW = wnB + 16*j + m16;
        wf[j] = *reinterpret_cast<const bf16x8*>(&Wb[rW*32 + ((quad ^ ((rW>>1)&3))<<3)]);
      }
      asm volatile("s_waitcnt lgkmcnt(0)" ::: "memory");
      __builtin_amdgcn_sched_barrier(0);
      __builtin_amdgcn_s_setprio(1);
      #pragma unroll
      for (int j = 0; j < 8; j++)
        accB[j] = __builtin_amdgcn_mfma_f32_16x16x32_bf16(af, wf[j], accB[j], 0, 0, 0);
      __builtin_amdgcn_s_setprio(0);
    }
  }

  // ---- final epilogue: h = accB + bo + y, two col-halves via zbuf ----
  #pragma unroll
  for (int n = 0; n < 2; n++){
    asm volatile("s_waitcnt lgkmcnt(0)" ::: "memory");
    __builtin_amdgcn_sched_barrier(0);
    __builtin_amdgcn_s_barrier();       // prior zbuf reads done (all waves)
    __builtin_amdgcn_sched_barrier(0);
    if ((wv >> 2) == n){
      #pragma unroll
      for (int j = 0; j < 8; j++){
        const int lcol = 16*j + m16;
        const float bb = bo[n*128 + lcol];
        #pragma unroll
        for (int r2 = 0; r2 < 4; r2++){
          const int lrow = wm + quad*4 + r2;
          float v = accB[j][r2] + bb;
          bf16 bv = __float2bfloat16(v);
          zbuf[lrow*132 + lcol] = *reinterpret_cast<unsigned short*>(&bv);
        }
      }
    }
    asm volatile("s_waitcnt lgkmcnt(0)" ::: "memory");
    __builtin_amdgcn_sched_barrier(0);
    __builtin_amdgcn_s_barrier();       // writes visible
    __builtin_amdgcn_sched_barrier(0);
    const int rr = tid >> 4, c16 = (tid & 15) * 8;   // rr 0..31
    #pragma unroll
    for (int s = 0; s < 2; s++){
      const int orow = s*32 + rr;
      uint4 hv = *reinterpret_cast<const uint4*>(&zbuf[orow*132 + c16]);
      const size_t go = (size_t)(row0 + orow)*HIDD + n*128 + c16;
      uint4 yv = *reinterpret_cast<const uint4*>(g_yb + go);
      uint4 o;
      o.x = bf2_add(hv.x, yv.x); o.y = bf2_add(hv.y, yv.y);
      o.z = bf2_add(hv.z, yv.z); o.w = bf2_add(hv.w, yv.w);
      *reinterpret_cast<uint4*>(g_hb + go) = o;
    }
  }
}

// ---------------------------------------------------------------------------
// fp32 tiled GEMMs for the small ends (embed, out) — proven R12 structure.
// ---------------------------------------------------------------------------
__global__ __launch_bounds__(256) void emb_gemm(
    const float* __restrict__ x, const float* __restrict__ W,
    const float* __restrict__ b)
{
  __shared__ __align__(16) float Asx[16][68];
  __shared__ __align__(16) float Wsx[16][68];
  const int tid = threadIdx.x;
  const int tx = tid & 15, ty = tid >> 4;
  const int row0 = blockIdx.y * 64, col0 = blockIdx.x * 64;
  const int lc = tid & 15, lr = tid >> 4;
  float acc[4][4] = {};
  for (int k0 = 0; k0 < INDIM; k0 += 16){
    #pragma unroll
    for (int i = 0; i < 4; i++){
      Asx[lc][lr + 16*i] = x[(size_t)(row0 + lr + 16*i)*INDIM + k0 + lc];
      Wsx[lc][lr + 16*i] = W[(size_t)(col0 + lr + 16*i)*INDIM + k0 + lc];
    }
    __syncthreads();
    #pragma unroll
    for (int k = 0; k < 16; k++){
      float4 av = *reinterpret_cast<const float4*>(&Asx[k][ty*4]);
      float4 bv = *reinterpret_cast<const float4*>(&Wsx[k][tx*4]);
      float a[4] = {av.x, av.y, av.z, av.w};
      float b2[4] = {bv.x, bv.y, bv.z, bv.w};
      #pragma unroll
      for (int i = 0; i < 4; i++)
        #pragma unroll
        for (int j = 0; j < 4; j++)
          acc[i][j] = fmaf(a[i], b2[j], acc[i][j]);
    }
    __syncthreads();
  }
  #pragma unroll
  for (int i = 0; i < 4; i++){
    const int r = row0 + ty*4 + i;
    #pragma unroll
    for (int j = 0; j < 4; j++){
      const int cn = col0 + tx*4 + j;
      g_hb[(size_t)r*HIDD + cn] = __float2bfloat16(acc[i][j] + b[cn]);
    }
  }
}

__global__ __launch_bounds__(256) void out_gemm(
    const float* __restrict__ W, const float* __restrict__ b,
    float* __restrict__ out)
{
  __shared__ __align__(16) float Asx[16][68];
  __shared__ __align__(16) float Wsx[16][68];
  const int tid = threadIdx.x;
  const int tx = tid & 15, ty = tid >> 4;
  const int row0 = blockIdx.y * 64, col0 = blockIdx.x * 64;
  const int lc = tid & 15, lr = tid >> 4;
  float acc[4][4] = {};
  for (int k0 = 0; k0 < HIDD; k0 += 16){
    #pragma unroll
    for (int i = 0; i < 4; i++){
      Asx[lc][lr + 16*i] = __bfloat162float(g_hb[(size_t)(row0 + lr + 16*i)*HIDD + k0 + lc]);
      Wsx[lc][lr + 16*i] = W[(size_t)(col0 + lr + 16*i)*HIDD + k0 + lc];
    }
    __syncthreads();
    #pragma unroll
    for (int k = 0; k < 16; k++){
      float4 av = *reinterpret_cast<const float4*>(&Asx[k][ty*4]);
      float4 bv = *reinterpret_cast<const float4*>(&Wsx[k][tx*4]);
      float a[4] = {av.x, av.y, av.z, av.w};
      float b2[4] = {bv.x, bv.y, bv.z, bv.w};
      #pragma unroll
      for (int i = 0; i < 4; i++)
        #pragma unroll
        for (int j = 0; j < 4; j++)
          acc[i][j] = fmaf(a[i], b2[j], acc[i][j]);
    }
    __syncthreads();
  }
  #pragma unroll
  for (int i = 0; i < 4; i++){
    const int r = row0 + ty*4 + i;
    #pragma unroll
    for (int j = 0; j < 4; j++){
      const int cn = col0 + tx*4 + j;
      out[(size_t)r*OUTD + cn] = acc[i][j] + b[cn];
    }
  }
}

// ---------------------------------------------------------------------------
// Prefix accumulate over chunk carries + local re-scan seeded with prefix.
// Interleaved layout: thread s owns complex state s at uint-paired cols.
// ---------------------------------------------------------------------------
__global__ __launch_bounds__(256) void scan_fix(
    const float* __restrict__ nu_log, const float* __restrict__ th_log)
{
  const int blk = blockIdx.x;
  const int c   = blk & (NCHUNK - 1);
  const int s   = threadIdx.x;
  float lr, li; lam_of(nu_log, th_log, s, lr, li);
  float cr = 0.f, ci = 0.f;
  if (c > 0){
    float Tr = lr, Ti = li;
    #pragma unroll
    for (int i = 0; i < 6; i++){ float nr = Tr*Tr - Ti*Ti; Ti = 2.f*Tr*Ti; Tr = nr; }
    const int bstart = blk - c;
    for (int j = 0; j < c; j++){
      float2 e = *reinterpret_cast<const float2*>(&g_carry[(size_t)(bstart + j)*512 + 2*s]);
      float nr = fmaf(Tr, cr, fmaf(-Ti, ci, e.x));
      float ni = fmaf(Tr, ci, fmaf( Ti, cr, e.y));
      cr = nr; ci = ni;
    }
  }
  float ar = cr, ai = ci;
  unsigned int* pb = reinterpret_cast<unsigned int*>(g_bub) + (size_t)blk*CHUNK*256 + s;
  for (int t = 0; t < CHUNK; t++){
    unsigned int pr = pb[(size_t)t*256];
    float br = __uint_as_float(pr << 16);
    float bi = __uint_as_float(pr & 0xffff0000u);
    float nr = fmaf(lr, ar, fmaf(-li, ai, br));
    float ni = fmaf(lr, ai, fmaf( li, ar, bi));
    ar = nr; ai = ni;
    bf16 hr = __float2bfloat16(ar), hi2 = __float2bfloat16(ai);
    unsigned int w = (unsigned int)(*reinterpret_cast<unsigned short*>(&hr))
                   | ((unsigned int)(*reinterpret_cast<unsigned short*>(&hi2)) << 16);
    pb[(size_t)t*256] = w;
  }
}

// Pack B_norm for ALL layers -> bf16, rows INTERLEAVED: row 2s=re_s, 2s+1=im_s
__global__ __launch_bounds__(256) void pack_B(
    const float* __restrict__ Bre, const float* __restrict__ Bim,
    const float* __restrict__ gl)
{
  int idx = blockIdx.x * 256 + threadIdx.x;
  int l = idx >> 16, within = idx & 65535;
  int s = within >> 8, h = within & 255;
  float g = expf(gl[l*STATE_D + s]);
  g_Bnb[(size_t)l*131072 + (size_t)(2*s  )*256 + h] = __float2bfloat16(Bre[idx] * g);
  g_Bnb[(size_t)l*131072 + (size_t)(2*s+1)*256 + h] = __float2bfloat16(Bim[idx] * g);
}

// Pack Cw for ALL layers -> bf16, cols INTERLEAVED: col 2s=Cre, 2s+1=-Cim
__global__ __launch_bounds__(256) void pack_C(
    const float* __restrict__ Cre, const float* __restrict__ Cim)
{
  int idx = blockIdx.x * 256 + threadIdx.x;
  int l = idx >> 16, within = idx & 65535;
  int h = within >> 8, s = within & 255;
  g_Cwb[(size_t)l*131072 + (size_t)h*512 + 2*s]     = __float2bfloat16( Cre[idx]);
  g_Cwb[(size_t)l*131072 + (size_t)h*512 + 2*s + 1] = __float2bfloat16(-Cim[idx]);
}

// Straight fp32 -> bf16 weight convert into selected buffer
__global__ __launch_bounds__(256) void conv_bf16(
    const float* __restrict__ src, int dstSel, int n)
{
  int i = blockIdx.x * 256 + threadIdx.x;
  if (i < n) bufb(dstSel)[i] = __float2bfloat16(src[i]);
}

// ---------------------------------------------------------------------------
extern "C" void kernel_launch(void* const* d_in, const int* in_sizes, int n_in,
                              void* d_out, int out_size, void* d_ws, size_t ws_size,
                              hipStream_t stream)
{
  (void)d_ws; (void)ws_size; (void)out_size; (void)n_in; (void)in_sizes;
  const float* x      = (const float*)d_in[0];
  const float* emb_W  = (const float*)d_in[1];
  const float* emb_b  = (const float*)d_in[2];
  const float* nu_log = (const float*)d_in[3];
  const float* th_log = (const float*)d_in[4];
  const float* ga_log = (const float*)d_in[5];
  const float* B_re   = (const float*)d_in[6];
  const float* B_im   = (const float*)d_in[7];
  const float* C_re   = (const float*)d_in[8];
  const float* C_im   = (const float*)d_in[9];
  const float* Dv     = (const float*)d_in[10];
  const float* Wh     = (const float*)d_in[11];
  const float* bh     = (const float*)d_in[12];
  const float* Wo     = (const float*)d_in[13];
  const float* bo     = (const float*)d_in[14];
  const float* out_W  = (const float*)d_in[15];
  const float* out_b  = (const float*)d_in[16];

  const dim3 blk(256);

  // ---- all weight packing upfront ----
  pack_B<<<dim3(NLAYERS*256), blk, 0, stream>>>(B_re, B_im, ga_log);
  pack_C<<<dim3(NLAYERS*256), blk, 0, stream>>>(C_re, C_im);
  conv_bf16<<<dim3(NLAYERS*1024), blk, 0, stream>>>(Wh, SB_WHB, NLAYERS*262144);
  conv_bf16<<<dim3(NLAYERS*1024), blk, 0, stream>>>(Wo, SB_WOB, NLAYERS*262144);

  // embed: h = x @ emb_W^T + emb_b  -> g_hb
  emb_gemm<<<dim3(HIDD/64, M_TOK/64), blk, 0, stream>>>(x, emb_W, emb_b);

  for (int l = 0; l < NLAYERS; l++){
    // Bu = h @ Bn^T (32768 x 512 x 256) -> g_bub bf16 + chunk carries
    mfma_gemm<0, 8><<<dim3(4, M_TOK/64), blk, 0, stream>>>(
        SB_HB, HIDD, SB_BNB, l*131072, HIDD, SB_BUB, 512,
        nullptr, -1, 0, nullptr, HIDD,
        nu_log + l*STATE_D, th_log + l*STATE_D);

    // prefix + rescan (in-place states)
    scan_fix<<<dim3(M_TOK/CHUNK), blk, 0, stream>>>(nu_log + l*STATE_D, th_log + l*STATE_D);

    // y = states @ Cw^T + D*h -> g_yb
    mfma_gemm<0, 4><<<dim3(2, M_TOK/64), blk, 0, stream>>>(
        SB_BUB, 512, SB_CWB, l*131072, 512, SB_YB, HIDD,
        nullptr, SB_HB, HIDD, Dv + l*HIDD, 512, nullptr, nullptr);

    // h = gelu(y @ Wh^T + bh) @ Wo^T + bo + y  (fused, 8-wave, 1-barrier rings)
    fused_mlp<<<dim3(M_TOK/64), dim3(512), 0, stream>>>(
        l*262144, l*262144, bh + l*MLPD, bo + l*HIDD);
  }

  // out = h @ out_W^T + out_b
  out_gemm<<<dim3(OUTD/64, M_TOK/64), blk, 0, stream>>>(out_W, out_b, (float*)d_out);
}